// Round 7
// baseline (3436.282 us; speedup 1.0000x reference)
//
#include <hip/hip_runtime.h>
#include <math.h>

#define NNODES 5000
#define NEDGES 50000
#define SEQT 12
#define NB 40000
#define NSB 157      // ceil(5000/32) node-slabs for hop1 prop grids
#define ECAP 768     // staged edges per 32-node slab
#define ECAP2 320    // staged edges per 8-node GEMM block (avg ~80)

typedef __attribute__((ext_vector_type(8))) _Float16 half8;
typedef __attribute__((ext_vector_type(2))) _Float16 half2v;
typedef __attribute__((ext_vector_type(4))) float f32x4;

// chunked tensor layout: [node][chunk=col>>3][batch][col&7]
// 64-wide: node stride 512 halves; 128-wide: 1024; XTh(32-wide): 256
__device__ __forceinline__ size_t cidx64(int row, int col){
    return (size_t)(row>>3)*512 + (size_t)((col>>3)*64) + (size_t)((row&7)*8) + (col&7);
}

// ---------------- setup kernels ----------------

__global__ void count_deg_k(const int* __restrict__ ei, int* deg_out, int* deg_in){
    int e = blockIdx.x*blockDim.x + threadIdx.x;
    if (e < NEDGES){
        atomicAdd(&deg_out[ei[e]], 1);
        atomicAdd(&deg_in[ei[NEDGES + e]], 1);
    }
}

__global__ void scan_k(const int* __restrict__ deg_in, int* __restrict__ row_ptr){
    __shared__ int part[256];
    int tid = threadIdx.x;
    int base = tid*20;
    int loc[20]; int s = 0;
    for (int i=0;i<20;i++){
        int idx = base+i;
        int v = (idx < NNODES) ? deg_in[idx] : 0;
        loc[i] = s; s += v;
    }
    part[tid] = s;
    __syncthreads();
    for (int off=1; off<256; off<<=1){
        int v = (tid>=off) ? part[tid-off] : 0;
        __syncthreads();
        part[tid] += v;
        __syncthreads();
    }
    int prev = (tid==0) ? 0 : part[tid-1];
    for (int i=0;i<20;i++){
        int idx = base+i;
        if (idx < NNODES) row_ptr[idx] = prev + loc[i];
    }
    if (tid==255) row_ptr[NNODES] = part[255];
}

__global__ void fill_csr_k(const int* __restrict__ ei, const int* __restrict__ deg_out,
                           const int* __restrict__ deg_in, const int* __restrict__ row_ptr,
                           int* cursor, int* __restrict__ csr_src,
                           float* __restrict__ csr_wo, float* __restrict__ csr_wi){
    int e = blockIdx.x*blockDim.x + threadIdx.x;
    if (e >= NEDGES) return;
    int s = ei[e], d = ei[NEDGES+e];
    int pos = atomicAdd(&cursor[d], 1);
    int slot = row_ptr[d] + pos;
    csr_src[slot] = s;
    csr_wo[slot] = 1.f/(float)deg_out[s];
    csr_wi[slot] = 1.f/(float)deg_in[d];
}

__global__ void prepack_x_k(const float* __restrict__ x, _Float16* __restrict__ Xtph){
    int idx = blockIdx.x*256 + threadIdx.x;
    if (idx >= SEQT*NB*2) return;
    int tt = idx / (NB*2);
    int r2 = idx - tt*(NB*2);
    int row = r2 >> 1, f = r2 & 1;
    int n = row >> 3, b = row & 7;
    Xtph[idx] = (_Float16)x[((size_t)(b*SEQT+tt)*NNODES + n)*2 + f];
}

// ---------------- weight packing (refolded basis, fp16, ks-major MFMA B-frag) ----------------
// refolded basis: {T0, T1o, T1i, U2o=PoT1o, U2i=PiT1i}
// slot 0: W'0 = W[0,0]+W[1,0]-W[0,2]-W[1,2]; 1: W[0,1]; 2: W[1,1]; 3: 2W[0,2]; 4: 2W[1,2]
__device__ __forceinline__ float wfetch(const float* __restrict__ W, int F, int slot, int f, int c){
    const float* p0 = W + ((size_t)0*F + f)*64 + c;
    const float* p1 = W + ((size_t)1*F + f)*64 + c;
    const float* p2 = W + ((size_t)2*F + f)*64 + c;
    const float* p3 = W + ((size_t)3*F + f)*64 + c;
    const float* p4 = W + ((size_t)4*F + f)*64 + c;
    const float* p5 = W + ((size_t)5*F + f)*64 + c;
    switch(slot){
        case 0: return *p0 + *p3 - *p2 - *p5;
        case 1: return *p1;
        case 2: return *p4;
        case 3: return 2.f * *p2;
        default: return 2.f * *p5;
    }
}

__global__ void pack_l0_k(const float* __restrict__ W, _Float16* __restrict__ wh){
    int idx = blockIdx.x*256 + threadIdx.x;
    if (idx >= 4*11*64) return;
    int lane = idx & 63, rest = idx >> 6;
    int ks = rest % 11, cf = rest / 11;
    int col = cf*16 + (lane & 15);
    int kb = ks*32 + ((lane>>4)<<3);
    size_t o = ((size_t)(ks*4 + cf)*64 + lane)*8;
    for (int j=0;j<8;j++){
        int k = kb + j;
        float v = 0.f;
        if (ks == 0){
            if (k < 10) v = wfetch(W, 66, k>>1, k&1, col);
        } else {
            int slot = (ks-1)>>1;
            int f = 2 + k - 32 - 64*slot;
            v = wfetch(W, 66, slot, f, col);
        }
        wh[o+j] = (_Float16)v;
    }
}

__global__ void pack_l1_k(const float* __restrict__ W, _Float16* __restrict__ wh){
    int idx = blockIdx.x*256 + threadIdx.x;
    if (idx >= 4*20*64) return;
    int lane = idx & 63, rest = idx >> 6;
    int ks = rest % 20, cf = rest / 20;
    int col = cf*16 + (lane & 15);
    int kb = ks*32 + ((lane>>4)<<3);
    int slot = ks >> 2;
    size_t o = ((size_t)(ks*4 + cf)*64 + lane)*8;
    for (int j=0;j<8;j++){
        int k = kb + j;
        int f = k - slot*128;
        wh[o+j] = (_Float16)wfetch(W, 128, slot, f, col);
    }
}

// ---------------- hop1 propagation kernels (chunked, CSR by dst) ----------------

#define EDGE_STAGE_DUAL \
    __shared__ int s_src[ECAP]; __shared__ float s_wo[ECAP], s_wi[ECAP]; \
    int n0 = nsb*32; \
    int n1 = n0+32 > NNODES ? NNODES : n0+32; \
    int eb = rp[n0], ee = rp[n1]; \
    int cnt = ee-eb < ECAP ? ee-eb : ECAP; \
    for (int j=threadIdx.x; j<cnt; j+=256){ \
        s_src[j] = cs[eb+j]; s_wo[j] = cwo[eb+j]; s_wi[j] = cwi[eb+j]; \
    } \
    __syncthreads(); \
    int nl = threadIdx.x >> 3, b = threadIdx.x & 7; \
    int n = n0 + nl; \
    if (n >= NNODES) return; \
    int beg = rp[n]-eb, end = rp[n+1]-eb;

// dual prop of a 64-wide chunked tensor: Yo = Po S, Yi = Pi S
__global__ __launch_bounds__(256) void k_dual64c(
    const _Float16* __restrict__ S,
    _Float16* __restrict__ Yo, _Float16* __restrict__ Yi,
    const int* __restrict__ rp, const int* __restrict__ cs,
    const float* __restrict__ cwo, const float* __restrict__ cwi){
    int c = blockIdx.x & 7, nsb = blockIdx.x >> 3;
    EDGE_STAGE_DUAL
    int off = c*64 + b*8;
    float ao[8]={0,0,0,0,0,0,0,0}, ai[8]={0,0,0,0,0,0,0,0};
    for (int j=beg; j<end; ++j){
        int src; float wo, wi;
        if (j < cnt){ src=s_src[j]; wo=s_wo[j]; wi=s_wi[j]; }
        else { src=cs[eb+j]; wo=cwo[eb+j]; wi=cwi[eb+j]; }
        half8 v = *(const half8*)(S + (size_t)src*512 + off);
        #pragma unroll
        for (int e=0;e<8;e++){
            float xv=(float)v[e];
            ao[e]=fmaf(wo,xv,ao[e]); ai[e]=fmaf(wi,xv,ai[e]);
        }
    }
    half8 po, pi;
    #pragma unroll
    for (int e=0;e<8;e++){ po[e]=(_Float16)ao[e]; pi[e]=(_Float16)ai[e]; }
    *(half8*)(Yo + (size_t)n*512 + off) = po;
    *(half8*)(Yi + (size_t)n*512 + off) = pi;
}

// L0 hop1: h-part (h0h chunked) -> Th1o/Th1i; x side-channel (c==0) -> XTh cols 0-5
__global__ __launch_bounds__(256) void k_dual_l0c(
    const _Float16* __restrict__ h0h, const _Float16* __restrict__ Xt,
    _Float16* __restrict__ T1o, _Float16* __restrict__ T1i, _Float16* __restrict__ XTh,
    const int* __restrict__ rp, const int* __restrict__ cs,
    const float* __restrict__ cwo, const float* __restrict__ cwi){
    int c = blockIdx.x & 7, nsb = blockIdx.x >> 3;
    EDGE_STAGE_DUAL
    int off = c*64 + b*8;
    float ao[8]={0,0,0,0,0,0,0,0}, ai[8]={0,0,0,0,0,0,0,0};
    float ax0=0,ax1=0, ay0=0,ay1=0;
    for (int j=beg; j<end; ++j){
        int src; float wo, wi;
        if (j < cnt){ src=s_src[j]; wo=s_wo[j]; wi=s_wi[j]; }
        else { src=cs[eb+j]; wo=cwo[eb+j]; wi=cwi[eb+j]; }
        half8 v = *(const half8*)(h0h + (size_t)src*512 + off);
        #pragma unroll
        for (int e=0;e<8;e++){
            float xv=(float)v[e];
            ao[e]=fmaf(wo,xv,ao[e]); ai[e]=fmaf(wi,xv,ai[e]);
        }
        if (c == 0){
            half2v xv = *(const half2v*)(Xt + (size_t)src*16 + b*2);
            float x0=(float)xv[0], x1=(float)xv[1];
            ax0=fmaf(wo,x0,ax0); ax1=fmaf(wo,x1,ax1);
            ay0=fmaf(wi,x0,ay0); ay1=fmaf(wi,x1,ay1);
        }
    }
    half8 po, pi;
    #pragma unroll
    for (int e=0;e<8;e++){ po[e]=(_Float16)ao[e]; pi[e]=(_Float16)ai[e]; }
    *(half8*)(T1o + (size_t)n*512 + off) = po;
    *(half8*)(T1i + (size_t)n*512 + off) = pi;
    if (c == 0){
        size_t ro = (size_t)n*256 + b*8;
        XTh[ro+0] = Xt[(size_t)(n*8+b)*2+0];
        XTh[ro+1] = Xt[(size_t)(n*8+b)*2+1];
        XTh[ro+2] = (_Float16)ax0; XTh[ro+3] = (_Float16)ax1;
        XTh[ro+4] = (_Float16)ay0; XTh[ro+5] = (_Float16)ay1;
    }
}

// L1 hop1: [h0h | h1h] -> 128-wide T1o/T1i (16 chunks)
__global__ __launch_bounds__(256) void k_dual_l1c(
    const _Float16* __restrict__ h0h, const _Float16* __restrict__ h1h,
    _Float16* __restrict__ T1o, _Float16* __restrict__ T1i,
    const int* __restrict__ rp, const int* __restrict__ cs,
    const float* __restrict__ cwo, const float* __restrict__ cwi){
    int cc = blockIdx.x & 15, nsb = blockIdx.x >> 4;
    const _Float16* S = (cc < 8) ? h0h : h1h;
    int soff_c = (cc & 7)*64;
    EDGE_STAGE_DUAL
    int soff = soff_c + b*8;
    float ao[8]={0,0,0,0,0,0,0,0}, ai[8]={0,0,0,0,0,0,0,0};
    for (int j=beg; j<end; ++j){
        int src; float wo, wi;
        if (j < cnt){ src=s_src[j]; wo=s_wo[j]; wi=s_wi[j]; }
        else { src=cs[eb+j]; wo=cwo[eb+j]; wi=cwi[eb+j]; }
        half8 v = *(const half8*)(S + (size_t)src*512 + soff);
        #pragma unroll
        for (int e=0;e<8;e++){
            float xv=(float)v[e];
            ao[e]=fmaf(wo,xv,ao[e]); ai[e]=fmaf(wi,xv,ai[e]);
        }
    }
    half8 po, pi;
    #pragma unroll
    for (int e=0;e<8;e++){ po[e]=(_Float16)ao[e]; pi[e]=(_Float16)ai[e]; }
    size_t o = (size_t)n*1024 + cc*64 + b*8;
    *(half8*)(T1o + o) = po;
    *(half8*)(T1i + o) = pi;
}

// ---------------- fused hop2 + MFMA GEMM ----------------
// Variants: 0 = L0 z/r (EPI sigmoid->Z,G0 + XTh 6-9 writeback), 1 = L0 h (GRU),
//           2 = L1 z/r, 3 = L1 h (GRU + fused proj)
// ks source codes: 0-5 global ptr idx; 6 xtile; 8..11 LDS tiles 0..3

struct FArgs { const _Float16* p[6]; };

__host__ __device__ constexpr int ks_src(int V, int ks){
    constexpr int T[4][20] = {
        {6,0,0,1,1,2,2,8,8,9,9, 0,0,0,0,0,0,0,0,0},
        {0,1,1,2,2,3,3,8,8,9,9, 0,0,0,0,0,0,0,0,0},
        {0,0,1,1,2,2,2,2,3,3,3,3,8,8,9,9,10,10,11,11},
        {0,0,1,1,2,2,3,3,4,4,5,5,8,8,9,9,10,10,11,11}};
    return T[V][ks];
}
__host__ __device__ constexpr int ks_off(int V, int ks){
    constexpr int T[4][20] = {
        {0,0,256,0,256,0,256,0,256,0,256, 0,0,0,0,0,0,0,0,0},
        {0,0,256,0,256,0,256,0,256,0,256, 0,0,0,0,0,0,0,0,0},
        {0,256,0,256,0,256,512,768,0,256,512,768,0,256,0,256,0,256,0,256},
        {0,256,0,256,0,256,0,256,0,256,0,256,0,256,0,256,0,256,0,256}};
    return T[V][ks];
}
__host__ __device__ constexpr int ks_st(int V, int ks){
    constexpr int T[4][20] = {
        {256,512,512,512,512,512,512,512,512,512,512, 0,0,0,0,0,0,0,0,0},
        {256,512,512,512,512,512,512,512,512,512,512, 0,0,0,0,0,0,0,0,0},
        {512,512,512,512,1024,1024,1024,1024,1024,1024,1024,1024,512,512,512,512,512,512,512,512},
        {512,512,512,512,1024,1024,512,512,1024,1024,512,512,512,512,512,512,512,512,512,512}};
    return T[V][ks];
}
__host__ __device__ constexpr int unit_src(int V, int u){
    constexpr int T[4][4] = {{1,2,0,0},{2,3,0,0},{2,2,3,3},{2,3,4,5}};
    return T[V][u];
}
__host__ __device__ constexpr int unit_off(int V, int u){
    constexpr int T[4][4] = {{0,0,0,0},{0,0,0,0},{0,512,0,512},{0,0,0,0}};
    return T[V][u];
}
__host__ __device__ constexpr int unit_st(int V, int u){
    constexpr int T[4][4] = {{512,512,0,0},{512,512,0,0},{1024,1024,1024,1024},{1024,512,1024,512}};
    return T[V][u];
}
__host__ __device__ constexpr int unit_dir(int V, int u){
    constexpr int T[4][4] = {{0,1,0,0},{0,1,0,0},{0,0,1,1},{0,0,1,1}};
    return T[V][u];
}

template<int V>
__global__ __launch_bounds__(256) void k_fgemm(
    FArgs fa, _Float16* __restrict__ xth,
    const _Float16* __restrict__ wh0, const float* __restrict__ b0,
    const _Float16* __restrict__ wh1, const float* __restrict__ b1,
    float* __restrict__ Z, _Float16* __restrict__ Gout,
    float* __restrict__ Hf, _Float16* __restrict__ Hh,
    const float* __restrict__ Wo, const float* __restrict__ bo,
    float* __restrict__ out, int t,
    const int* __restrict__ rp, const int* __restrict__ cs,
    const float* __restrict__ cwo, const float* __restrict__ cwi){

    constexpr int NK = (V<2)?11:20;
    constexpr int NG = (V==0||V==2)?2:1;
    constexpr int NU = (V<2)?2:4;
    constexpr bool XSP = (V==0);
    constexpr int EPI = (V==0||V==2)?0:((V==1)?1:2);

    __shared__ _Float16 ldsb[2][NG*2048];
    __shared__ _Float16 tiles[NU*4096 + (XSP?2048:0)];
    __shared__ int se_s[ECAP2]; __shared__ float se_o[ECAP2], se_i[ECAP2];
    __shared__ int rpl[9];
    __shared__ float spr[4][32];

    const int tid = threadIdx.x;
    const int lane = tid & 63, wv = tid >> 6, rl = lane & 15, kg = lane >> 4;
    const int n0 = blockIdx.x*8;

    // ---- stage edges for this block's 8 nodes ----
    int eb = rp[n0], ee = rp[n0+8];
    int cnt = (ee-eb) < ECAP2 ? (ee-eb) : ECAP2;
    for (int j=tid; j<cnt; j+=256){
        se_s[j] = cs[eb+j]; se_o[j] = cwo[eb+j]; se_i[j] = cwi[eb+j];
    }
    if (tid < 9) rpl[tid] = rp[n0+tid];
    __syncthreads();

    // ---- local hop2: compute T2/U2/G2 tiles into LDS (chunked, stride 512/node) ----
    #pragma unroll
    for (int u=0; u<NU; ++u){
        const _Float16* up = fa.p[unit_src(V,u)];
        const int uo = unit_off(V,u), us = unit_st(V,u), ud = unit_dir(V,u);
        #pragma unroll
        for (int rep=0; rep<2; ++rep){
            int it = tid + rep*256;
            int nl = it>>6, b=(it>>3)&7, ch=it&7;
            int jb = rpl[nl]-eb, je = rpl[nl+1]-eb;
            float acc[8] = {0,0,0,0,0,0,0,0};
            for (int j=jb; j<je; ++j){
                int src; float w;
                if (j < cnt){ src=se_s[j]; w = ud ? se_i[j] : se_o[j]; }
                else { src=cs[eb+j]; w = ud ? cwi[eb+j] : cwo[eb+j]; }
                half8 v = *(const half8*)(up + (size_t)src*us + uo + ch*64 + b*8);
                #pragma unroll
                for (int e=0;e<8;e++) acc[e]=fmaf(w,(float)v[e],acc[e]);
            }
            half8 pv;
            #pragma unroll
            for (int e=0;e<8;e++) pv[e]=(_Float16)acc[e];
            *(half8*)&tiles[u*4096 + nl*512 + ch*64 + b*8] = pv;
        }
    }
    if constexpr (XSP){
        // fill xtile (ks0 A image, 32 cols): 0-5 copy from XTh, 6-9 = T2x, 10-31 zero
        int nl = tid>>5, b=(tid>>2)&7, ch=tid&3;
        int n = n0 + nl;
        half8 val = {(_Float16)0,(_Float16)0,(_Float16)0,(_Float16)0,
                     (_Float16)0,(_Float16)0,(_Float16)0,(_Float16)0};
        int jb = rpl[nl]-eb, je = rpl[nl+1]-eb;
        if (ch == 0){
            #pragma unroll
            for (int c=0;c<6;c++) val[c] = xth[(size_t)n*256 + b*8 + c];
            float a6=0, a7=0;
            for (int j=jb;j<je;++j){
                int src; float w;
                if (j<cnt){ src=se_s[j]; w=se_o[j]; } else { src=cs[eb+j]; w=cwo[eb+j]; }
                half2v xv = *(const half2v*)(xth + (size_t)src*256 + b*8 + 2);
                a6=fmaf(w,(float)xv[0],a6); a7=fmaf(w,(float)xv[1],a7);
            }
            val[6]=(_Float16)a6; val[7]=(_Float16)a7;
            xth[(size_t)n*256 + b*8 + 6] = val[6];
            xth[(size_t)n*256 + b*8 + 7] = val[7];
        } else if (ch == 1){
            float a0=0, a1=0;
            for (int j=jb;j<je;++j){
                int src; float w;
                if (j<cnt){ src=se_s[j]; w=se_i[j]; } else { src=cs[eb+j]; w=cwi[eb+j]; }
                half2v xv = *(const half2v*)(xth + (size_t)src*256 + b*8 + 4);
                a0=fmaf(w,(float)xv[0],a0); a1=fmaf(w,(float)xv[1],a1);
            }
            val[0]=(_Float16)a0; val[1]=(_Float16)a1;
            xth[(size_t)n*256 + 64 + b*8 + 0] = val[0];
            xth[(size_t)n*256 + 64 + b*8 + 1] = val[1];
        }
        *(half8*)&tiles[NU*4096 + nl*256 + ch*64 + b*8] = val;
    }

    // ---- B pipeline prologue ----
    const _Float16* wsrc[2] = {wh0, wh1};
    half8 srg[NG];
    auto sload = [&](int ks){
        #pragma unroll
        for (int j=0;j<NG;j++)
            srg[j] = *(const half8*)(wsrc[j] + (size_t)ks*2048 + tid*8);
    };
    auto swrite = [&](int buf){
        #pragma unroll
        for (int j=0;j<NG;j++)
            *(half8*)&ldsb[buf][j*2048 + tid*8] = srg[j];
    };
    auto aload = [&](int ksx, half8& x0, half8& x1){
        const _Float16* base = fa.p[ks_src(V,ksx)];
        const int st = ks_st(V,ksx), of = ks_off(V,ksx);
        int r0 = blockIdx.x*64 + (wv&1)*32 + rl;
        int r1 = r0 + 16;
        x0 = *(const half8*)(base + (size_t)(r0>>3)*st + of + kg*64 + (r0&7)*8);
        x1 = *(const half8*)(base + (size_t)(r1>>3)*st + of + kg*64 + (r1&7)*8);
    };

    f32x4 acc[NG][2][2];
    #pragma unroll
    for (int g=0; g<NG; ++g)
        #pragma unroll
        for (int cc=0; cc<2; ++cc)
            #pragma unroll
            for (int mr=0; mr<2; ++mr){
                acc[g][cc][mr][0]=0.f; acc[g][cc][mr][1]=0.f;
                acc[g][cc][mr][2]=0.f; acc[g][cc][mr][3]=0.f;
            }

    half8 a0g, a1g, a0n, a1n;
    sload(0); swrite(0);
    sload(1);
    if (ks_src(V,0) < 6) aload(0, a0g, a1g);
    __syncthreads();

    #pragma unroll
    for (int ks=0; ks<NK; ++ks){
        const int cur = ks & 1;
        if (ks+1 < NK) swrite(cur^1);
        if (ks+2 < NK) sload(ks+2);
        half8 ax0, ax1;
        if (ks_src(V,ks) < 6){ ax0 = a0g; ax1 = a1g; }
        else {
            const int lbase = (ks_src(V,ks)==6) ? NU*4096 : (ks_src(V,ks)-8)*4096;
            const int lst = ks_st(V,ks), lo = ks_off(V,ks);
            int lr0 = (wv&1)*32 + rl, lr1 = lr0 + 16;
            ax0 = *(const half8*)&tiles[lbase + (lr0>>3)*lst + lo + kg*64 + (lr0&7)*8];
            ax1 = *(const half8*)&tiles[lbase + (lr1>>3)*lst + lo + kg*64 + (lr1&7)*8];
        }
        if (ks+1 < NK && ks_src(V,ks+1) < 6) aload(ks+1, a0n, a1n);
        #pragma unroll
        for (int g=0; g<NG; ++g){
            #pragma unroll
            for (int cc=0; cc<2; ++cc){
                half8 bv = *(const half8*)&ldsb[cur][g*2048 + ((wv>>1)*2+cc)*512 + lane*8];
                acc[g][cc][0] = __builtin_amdgcn_mfma_f32_16x16x32_f16(ax0, bv, acc[g][cc][0], 0, 0, 0);
                acc[g][cc][1] = __builtin_amdgcn_mfma_f32_16x16x32_f16(ax1, bv, acc[g][cc][1], 0, 0, 0);
            }
        }
        __syncthreads();
        a0g = a0n; a1g = a1n;
    }

    const int m0 = blockIdx.x*64 + (wv&1)*32;
    const int cfb = (wv>>1)*2;
    if constexpr (EPI == 0){
        #pragma unroll
        for (int cc=0; cc<2; ++cc){
            const int col = (cfb+cc)*16 + rl;
            float bzv = b0[col], brv = b1[col];
            #pragma unroll
            for (int mr=0; mr<2; ++mr)
                #pragma unroll
                for (int i=0;i<4;i++){
                    int row = m0 + mr*16 + kg*4 + i;
                    float z = 1.f/(1.f+__expf(-(acc[0][cc][mr][i] + bzv)));
                    float r = 1.f/(1.f+__expf(-(acc[NG-1][cc][mr][i] + brv)));
                    size_t ix = (size_t)row*64 + col;
                    Z[ix] = z;
                    Gout[cidx64(row,col)] = (_Float16)(Hf[ix]*r);
                }
        }
    } else {
        float pr[2][4] = {{0.f,0.f,0.f,0.f},{0.f,0.f,0.f,0.f}};
        #pragma unroll
        for (int cc=0; cc<2; ++cc){
            const int col = (cfb+cc)*16 + rl;
            float bv = b0[col];
            float wo_c = 0.f;
            if constexpr (EPI == 2) wo_c = Wo[col];
            #pragma unroll
            for (int mr=0; mr<2; ++mr)
                #pragma unroll
                for (int i=0;i<4;i++){
                    int row = m0 + mr*16 + kg*4 + i;
                    float ht = tanhf(acc[0][cc][mr][i] + bv);
                    size_t ix = (size_t)row*64 + col;
                    float z = Z[ix];
                    float hn = z*Hf[ix] + (1.f-z)*ht;
                    Hf[ix] = hn;
                    Hh[cidx64(row,col)] = (_Float16)hn;
                    if constexpr (EPI == 2) pr[mr][i] = fmaf(hn, wo_c, pr[mr][i]);
                }
        }
        if constexpr (EPI == 2){
            #pragma unroll
            for (int mr=0; mr<2; ++mr)
                #pragma unroll
                for (int i=0;i<4;i++){
                    float v = pr[mr][i];
                    v += __shfl_xor(v, 1);
                    v += __shfl_xor(v, 2);
                    v += __shfl_xor(v, 4);
                    v += __shfl_xor(v, 8);
                    if (rl == 0) spr[wv][mr*16 + kg*4 + i] = v;
                }
            __syncthreads();
            if (tid < 64){
                int r = tid;
                float v = spr[r>>5][r&31] + spr[(r>>5)|2][r&31] + bo[0];
                int row = blockIdx.x*64 + r;
                int n = row >> 3, b = row & 7;
                out[(size_t)(b*SEQT + t)*NNODES + n] = v;
            }
        }
    }
}

// ---------------- launcher ----------------

extern "C" void kernel_launch(void* const* d_in, const int* in_sizes, int n_in,
                              void* d_out, int out_size, void* d_ws, size_t ws_size,
                              hipStream_t stream){
    (void)in_sizes; (void)n_in; (void)out_size; (void)ws_size;
    const float* x  = (const float*)d_in[0];
    const int*   ei = (const int*)d_in[1];
    const float* Wz[2] = {(const float*)d_in[2],  (const float*)d_in[8]};
    const float* bz[2] = {(const float*)d_in[3],  (const float*)d_in[9]};
    const float* Wr[2] = {(const float*)d_in[4],  (const float*)d_in[10]};
    const float* br[2] = {(const float*)d_in[5],  (const float*)d_in[11]};
    const float* Wh[2] = {(const float*)d_in[6],  (const float*)d_in[12]};
    const float* bh[2] = {(const float*)d_in[7],  (const float*)d_in[13]};
    const float* Wo = (const float*)d_in[14];
    const float* bo = (const float*)d_in[15];
    float* out = (float*)d_out;

    char* p = (char*)d_ws;
    auto alloc = [&](size_t bytes)->char*{
        char* r = p; p += (bytes + 255) & ~(size_t)255; return r;
    };
    const size_t H64  = (size_t)NB*64*2;
    const size_t H128 = (size_t)NB*128*2;
    const size_t F64  = (size_t)NB*64*4;

    _Float16* Xtph = (_Float16*)alloc((size_t)SEQT*NB*2*2);
    float*    h0f = (float*)alloc(F64);
    float*    h1f = (float*)alloc(F64);
    float*    Z0  = (float*)alloc(F64);
    float*    Z1  = (float*)alloc(F64);
    _Float16* h0h = (_Float16*)alloc(H64);
    _Float16* h1h = (_Float16*)alloc(H64);
    _Float16* XTh = (_Float16*)alloc((size_t)NB*32*2);
    _Float16* Th1o = (_Float16*)alloc(H64);
    _Float16* Th1i = (_Float16*)alloc(H64);
    _Float16* G0L0 = (_Float16*)alloc(H64);
    _Float16* G1o0 = (_Float16*)alloc(H64);
    _Float16* G1i0 = (_Float16*)alloc(H64);
    _Float16* T1o128 = (_Float16*)alloc(H128);
    _Float16* T1i128 = (_Float16*)alloc(H128);
    _Float16* G0p  = (_Float16*)alloc(H64);
    _Float16* G1o1 = (_Float16*)alloc(H64);
    _Float16* G1i1 = (_Float16*)alloc(H64);
    _Float16 *whl0[3], *whl1[3];
    for (int g=0; g<3; ++g){
        whl0[g] = (_Float16*)alloc((size_t)4*11*64*8*2);
        whl1[g] = (_Float16*)alloc((size_t)4*20*64*8*2);
    }
    int* deg_out = (int*)alloc(NNODES*4);
    int* deg_in  = (int*)alloc(NNODES*4);
    int* row_ptr = (int*)alloc((NNODES+1)*4);
    int* cursor  = (int*)alloc(NNODES*4);
    int* csr_src = (int*)alloc(NEDGES*4);
    float* csr_wo = (float*)alloc(NEDGES*4);
    float* csr_wi = (float*)alloc(NEDGES*4);

    hipMemsetAsync(deg_out, 0, NNODES*4, stream);
    hipMemsetAsync(deg_in,  0, NNODES*4, stream);
    hipMemsetAsync(cursor,  0, NNODES*4, stream);
    hipMemsetAsync(h0f, 0, F64, stream);
    hipMemsetAsync(h1f, 0, F64, stream);
    hipMemsetAsync(h0h, 0, H64, stream);
    hipMemsetAsync(h1h, 0, H64, stream);
    hipMemsetAsync(XTh, 0, (size_t)NB*32*2, stream);

    count_deg_k<<<(NEDGES+255)/256, 256, 0, stream>>>(ei, deg_out, deg_in);
    scan_k<<<1, 256, 0, stream>>>(deg_in, row_ptr);
    fill_csr_k<<<(NEDGES+255)/256, 256, 0, stream>>>(ei, deg_out, deg_in, row_ptr,
                                                     cursor, csr_src, csr_wo, csr_wi);
    prepack_x_k<<<(SEQT*NB*2+255)/256, 256, 0, stream>>>(x, Xtph);
    const float* Wptr0[3] = {Wz[0], Wr[0], Wh[0]};
    const float* Wptr1[3] = {Wz[1], Wr[1], Wh[1]};
    for (int g=0; g<3; ++g){
        pack_l0_k<<<(4*11*64+255)/256, 256, 0, stream>>>(Wptr0[g], whl0[g]);
        pack_l1_k<<<(4*20*64+255)/256, 256, 0, stream>>>(Wptr1[g], whl1[g]);
    }

    FArgs fa0, fa1, fa2, fa3;
    fa0.p[0]=h0h;  fa0.p[1]=Th1o;   fa0.p[2]=Th1i;   fa0.p[3]=XTh;    fa0.p[4]=nullptr; fa0.p[5]=nullptr;
    fa1.p[0]=XTh;  fa1.p[1]=G0L0;   fa1.p[2]=G1o0;   fa1.p[3]=G1i0;   fa1.p[4]=nullptr; fa1.p[5]=nullptr;
    fa2.p[0]=h0h;  fa2.p[1]=h1h;    fa2.p[2]=T1o128; fa2.p[3]=T1i128; fa2.p[4]=nullptr; fa2.p[5]=nullptr;
    fa3.p[0]=h0h;  fa3.p[1]=G0p;    fa3.p[2]=T1o128; fa3.p[3]=G1o1;   fa3.p[4]=T1i128;  fa3.p[5]=G1i1;

    for (int t=0; t<SEQT; ++t){
        // ---- layer 0 ----
        k_dual_l0c<<<NSB*8, 256, 0, stream>>>(h0h, Xtph + (size_t)t*NB*2, Th1o, Th1i, XTh,
                                              row_ptr, csr_src, csr_wo, csr_wi);
        k_fgemm<0><<<NB/64, 256, 0, stream>>>(fa0, XTh,
            whl0[0], bz[0], whl0[1], br[0],
            Z0, G0L0, h0f, nullptr, nullptr, nullptr, nullptr, 0,
            row_ptr, csr_src, csr_wo, csr_wi);
        k_dual64c<<<NSB*8, 256, 0, stream>>>(G0L0, G1o0, G1i0, row_ptr, csr_src, csr_wo, csr_wi);
        k_fgemm<1><<<NB/64, 256, 0, stream>>>(fa1, XTh,
            whl0[2], bh[0], nullptr, nullptr,
            Z0, nullptr, h0f, h0h, nullptr, nullptr, nullptr, 0,
            row_ptr, csr_src, csr_wo, csr_wi);
        // ---- layer 1 ----
        k_dual_l1c<<<NSB*16, 256, 0, stream>>>(h0h, h1h, T1o128, T1i128,
                                               row_ptr, csr_src, csr_wo, csr_wi);
        k_fgemm<2><<<NB/64, 256, 0, stream>>>(fa2, XTh,
            whl1[0], bz[1], whl1[1], br[1],
            Z1, G0p, h1f, nullptr, nullptr, nullptr, nullptr, 0,
            row_ptr, csr_src, csr_wo, csr_wi);
        k_dual64c<<<NSB*8, 256, 0, stream>>>(G0p, G1o1, G1i1, row_ptr, csr_src, csr_wo, csr_wi);
        k_fgemm<3><<<NB/64, 256, 0, stream>>>(fa3, XTh,
            whl1[2], bh[1], nullptr, nullptr,
            Z1, nullptr, h1f, h1h, Wo, bo, out, t,
            row_ptr, csr_src, csr_wo, csr_wi);
    }
}

// Round 8
// 2408.974 us; speedup vs baseline: 1.4265x; 1.4265x over previous
//
#include <hip/hip_runtime.h>
#include <math.h>

#define NNODES 5000
#define NEDGES 50000
#define SEQT 12
#define NB 40000
#define MAXDEG 128

typedef __attribute__((ext_vector_type(8))) _Float16 half8;
typedef __attribute__((ext_vector_type(2))) _Float16 half2v;
typedef __attribute__((ext_vector_type(4))) float f32x4;

// ---------------- setup kernels ----------------

__global__ void count_deg_k(const int* __restrict__ ei, int* deg_out, int* deg_in){
    int e = blockIdx.x*blockDim.x + threadIdx.x;
    if (e < NEDGES){
        atomicAdd(&deg_out[ei[e]], 1);
        atomicAdd(&deg_in[ei[NEDGES + e]], 1);
    }
}

__global__ void scan_k(const int* __restrict__ deg_in, int* __restrict__ row_ptr){
    __shared__ int part[256];
    int tid = threadIdx.x;
    int base = tid*20;
    int loc[20]; int s = 0;
    for (int i=0;i<20;i++){
        int idx = base+i;
        int v = (idx < NNODES) ? deg_in[idx] : 0;
        loc[i] = s; s += v;
    }
    part[tid] = s;
    __syncthreads();
    for (int off=1; off<256; off<<=1){
        int v = (tid>=off) ? part[tid-off] : 0;
        __syncthreads();
        part[tid] += v;
        __syncthreads();
    }
    int prev = (tid==0) ? 0 : part[tid-1];
    for (int i=0;i<20;i++){
        int idx = base+i;
        if (idx < NNODES) row_ptr[idx] = prev + loc[i];
    }
    if (tid==255) row_ptr[NNODES] = part[255];
}

__global__ void fill_csr_k(const int* __restrict__ ei, const int* __restrict__ deg_out,
                           const int* __restrict__ deg_in, const int* __restrict__ row_ptr,
                           int* cursor, int* __restrict__ csr_src,
                           float* __restrict__ csr_wo, float* __restrict__ csr_wi){
    int e = blockIdx.x*blockDim.x + threadIdx.x;
    if (e >= NEDGES) return;
    int s = ei[e], d = ei[NEDGES+e];
    int pos = atomicAdd(&cursor[d], 1);
    int slot = row_ptr[d] + pos;
    csr_src[slot] = s;
    csr_wo[slot] = 1.f/(float)deg_out[s];
    csr_wi[slot] = 1.f/(float)deg_in[d];
}

// pre-pack x for all timesteps: Xtph[t][row][2] fp16, row = n*8+b
__global__ void prepack_x_k(const float* __restrict__ x, _Float16* __restrict__ Xtph){
    int idx = blockIdx.x*256 + threadIdx.x;
    if (idx >= SEQT*NB*2) return;
    int tt = idx / (NB*2);
    int r2 = idx - tt*(NB*2);
    int row = r2 >> 1, f = r2 & 1;
    int n = row >> 3, b = row & 7;
    Xtph[idx] = (_Float16)x[((size_t)(b*SEQT+tt)*NNODES + n)*2 + f];
}

// ---------------- weight packing (refolded basis, fp16, ks-major MFMA B-frag layout) ----------------
// refolded basis: {T0, T1o, T1i, U2o=Po T1o, U2i=Pi T1i}
// slot 0: W'0 = W[0,0]+W[1,0]-W[0,2]-W[1,2]; 1: W[0,1]; 2: W[1,1]; 3: 2W[0,2]; 4: 2W[1,2]
__device__ __forceinline__ float wfetch(const float* __restrict__ W, int F, int slot, int f, int c){
    const float* p0 = W + ((size_t)0*F + f)*64 + c;
    const float* p1 = W + ((size_t)1*F + f)*64 + c;
    const float* p2 = W + ((size_t)2*F + f)*64 + c;
    const float* p3 = W + ((size_t)3*F + f)*64 + c;
    const float* p4 = W + ((size_t)4*F + f)*64 + c;
    const float* p5 = W + ((size_t)5*F + f)*64 + c;
    switch(slot){
        case 0: return *p0 + *p3 - *p2 - *p5;
        case 1: return *p1;
        case 2: return *p4;
        case 3: return 2.f * *p2;
        default: return 2.f * *p5;
    }
}

// L0: nk=11. blk0 = XT block; blk 1+2s, 2+2s (s=0..4): slot s, h-rows f = 2 + (k - (1+2s)*32)
__global__ void pack_l0_k(const float* __restrict__ W, _Float16* __restrict__ wh){
    int idx = blockIdx.x*256 + threadIdx.x;
    if (idx >= 4*11*64) return;
    int lane = idx & 63, rest = idx >> 6;
    int ks = rest % 11, cf = rest / 11;
    int col = cf*16 + (lane & 15);
    int kb = ks*32 + ((lane>>4)<<3);
    size_t o = ((size_t)(ks*4 + cf)*64 + lane)*8;
    for (int j=0;j<8;j++){
        int k = kb + j;
        float v = 0.f;
        if (ks == 0){
            if (k < 10) v = wfetch(W, 66, k>>1, k&1, col);
        } else {
            int slot = (ks-1)>>1;
            int f = 2 + k - 32 - 64*slot;
            v = wfetch(W, 66, slot, f, col);
        }
        wh[o+j] = (_Float16)v;
    }
}

// L1: nk=20: ks>>2 = slot; f = k - slot*128
__global__ void pack_l1_k(const float* __restrict__ W, _Float16* __restrict__ wh){
    int idx = blockIdx.x*256 + threadIdx.x;
    if (idx >= 4*20*64) return;
    int lane = idx & 63, rest = idx >> 6;
    int ks = rest % 20, cf = rest / 20;
    int col = cf*16 + (lane & 15);
    int kb = ks*32 + ((lane>>4)<<3);
    int slot = ks >> 2;
    size_t o = ((size_t)(ks*4 + cf)*64 + lane)*8;
    for (int j=0;j<8;j++){
        int k = kb + j;
        int f = k - slot*128;
        wh[o+j] = (_Float16)wfetch(W, 128, slot, f, col);
    }
}

// ---------------- propagation kernels (fp16, 16B-granule gathers, CSR by dst) ----------------

template<int WH>
__global__ __launch_bounds__(WH) void k_dualh(
    const _Float16* __restrict__ S,
    _Float16* __restrict__ Yo, _Float16* __restrict__ Yi,
    const int* __restrict__ rp, const int* __restrict__ cs,
    const float* __restrict__ cwo, const float* __restrict__ cwi){
    constexpr int SLAB = 8*WH;
    int n = blockIdx.x;
    int beg = rp[n], deg = rp[n+1]-beg;
    int nst = deg < MAXDEG ? deg : MAXDEG;
    __shared__ int s_o[MAXDEG]; __shared__ float swo[MAXDEG], swi[MAXDEG];
    for (int j=threadIdx.x; j<nst; j+=WH){
        s_o[j] = cs[beg+j]*SLAB;
        swo[j] = cwo[beg+j]; swi[j] = cwi[beg+j];
    }
    __syncthreads();
    int off = threadIdx.x*8;
    float ao[8] = {0,0,0,0,0,0,0,0}, ai[8] = {0,0,0,0,0,0,0,0};
    for (int j=0;j<nst;j++){
        half8 v = *(const half8*)(S + s_o[j] + off);
        float wo=swo[j], wi=swi[j];
        #pragma unroll
        for (int e=0;e<8;e++){
            float xv = (float)v[e];
            ao[e]=fmaf(wo,xv,ao[e]); ai[e]=fmaf(wi,xv,ai[e]);
        }
    }
    for (int j=nst;j<deg;j++){
        half8 v = *(const half8*)(S + (size_t)cs[beg+j]*SLAB + off);
        float wo=cwo[beg+j], wi=cwi[beg+j];
        #pragma unroll
        for (int e=0;e<8;e++){
            float xv = (float)v[e];
            ao[e]=fmaf(wo,xv,ao[e]); ai[e]=fmaf(wi,xv,ai[e]);
        }
    }
    half8 po, pi;
    #pragma unroll
    for (int e=0;e<8;e++){ po[e]=(_Float16)ao[e]; pi[e]=(_Float16)ai[e]; }
    *(half8*)(Yo + (size_t)n*SLAB + off) = po;
    *(half8*)(Yi + (size_t)n*SLAB + off) = pi;
}

template<int WH>
__global__ __launch_bounds__(WH) void k_prop2h(
    const _Float16* __restrict__ T1o, const _Float16* __restrict__ T1i,
    _Float16* __restrict__ U2o, _Float16* __restrict__ U2i,
    const int* __restrict__ rp, const int* __restrict__ cs,
    const float* __restrict__ cwo, const float* __restrict__ cwi){
    constexpr int SLAB = 8*WH;
    int bx = blockIdx.x;
    int n = bx >> 1, sel = bx & 1;
    const _Float16* S = sel ? T1i : T1o;
    _Float16* U = sel ? U2i : U2o;
    const float* cw = sel ? cwi : cwo;
    int beg = rp[n], deg = rp[n+1]-beg;
    int nst = deg < MAXDEG ? deg : MAXDEG;
    __shared__ int s_o[MAXDEG]; __shared__ float s_w[MAXDEG];
    for (int j=threadIdx.x; j<nst; j+=WH){
        s_o[j] = cs[beg+j]*SLAB;
        s_w[j] = cw[beg+j];
    }
    __syncthreads();
    int off = threadIdx.x*8;
    float a[8] = {0,0,0,0,0,0,0,0};
    for (int j=0;j<nst;j++){
        half8 v = *(const half8*)(S + s_o[j] + off);
        float w=s_w[j];
        #pragma unroll
        for (int e=0;e<8;e++) a[e]=fmaf(w,(float)v[e],a[e]);
    }
    for (int j=nst;j<deg;j++){
        half8 v = *(const half8*)(S + (size_t)cs[beg+j]*SLAB + off);
        float w=cw[beg+j];
        #pragma unroll
        for (int e=0;e<8;e++) a[e]=fmaf(w,(float)v[e],a[e]);
    }
    half8 p;
    #pragma unroll
    for (int e=0;e<8;e++) p[e]=(_Float16)a[e];
    *(half8*)(U + (size_t)n*SLAB + off) = p;
}

__global__ __launch_bounds__(64) void k_dual_l0zrh(
    const _Float16* __restrict__ h0h, const _Float16* __restrict__ Xt,
    _Float16* __restrict__ T1o, _Float16* __restrict__ T1i, _Float16* __restrict__ XTh,
    const int* __restrict__ rp, const int* __restrict__ cs,
    const float* __restrict__ cwo, const float* __restrict__ cwi){
    int n = blockIdx.x;
    int beg = rp[n], deg = rp[n+1]-beg;
    int nst = deg < MAXDEG ? deg : MAXDEG;
    __shared__ int s_o[MAXDEG]; __shared__ float swo[MAXDEG], swi[MAXDEG];
    for (int j=threadIdx.x; j<nst; j+=64){
        s_o[j] = cs[beg+j]*512;
        swo[j] = cwo[beg+j]; swi[j] = cwi[beg+j];
    }
    __syncthreads();
    int off = threadIdx.x*8;
    {
        float ao[8] = {0,0,0,0,0,0,0,0}, ai[8] = {0,0,0,0,0,0,0,0};
        for (int j=0;j<nst;j++){
            half8 v = *(const half8*)(h0h + s_o[j] + off);
            float wo=swo[j], wi=swi[j];
            #pragma unroll
            for (int e=0;e<8;e++){
                float xv = (float)v[e];
                ao[e]=fmaf(wo,xv,ao[e]); ai[e]=fmaf(wi,xv,ai[e]);
            }
        }
        for (int j=nst;j<deg;j++){
            half8 v = *(const half8*)(h0h + (size_t)cs[beg+j]*512 + off);
            float wo=cwo[beg+j], wi=cwi[beg+j];
            #pragma unroll
            for (int e=0;e<8;e++){
                float xv = (float)v[e];
                ao[e]=fmaf(wo,xv,ao[e]); ai[e]=fmaf(wi,xv,ai[e]);
            }
        }
        half8 po, pi;
        #pragma unroll
        for (int e=0;e<8;e++){ po[e]=(_Float16)ao[e]; pi[e]=(_Float16)ai[e]; }
        *(half8*)(T1o + (size_t)n*512 + off) = po;
        *(half8*)(T1i + (size_t)n*512 + off) = pi;
    }
    if (threadIdx.x < 8){
        int b = threadIdx.x;
        float ax0=0,ax1=0, ay0=0,ay1=0;
        for (int j=0;j<nst;j++){
            int src = s_o[j] >> 9;
            half2v v = *(const half2v*)(Xt + src*16 + b*2);
            float x0=(float)v[0], x1=(float)v[1];
            ax0=fmaf(swo[j],x0,ax0); ax1=fmaf(swo[j],x1,ax1);
            ay0=fmaf(swi[j],x0,ay0); ay1=fmaf(swi[j],x1,ay1);
        }
        for (int j=nst;j<deg;j++){
            int src = cs[beg+j];
            half2v v = *(const half2v*)(Xt + src*16 + b*2);
            float x0=(float)v[0], x1=(float)v[1];
            ax0=fmaf(cwo[beg+j],x0,ax0); ax1=fmaf(cwo[beg+j],x1,ax1);
            ay0=fmaf(cwi[beg+j],x0,ay0); ay1=fmaf(cwi[beg+j],x1,ay1);
        }
        size_t ro = (size_t)(n*8 + b)*32;
        XTh[ro+0] = Xt[(size_t)(n*8+b)*2+0];
        XTh[ro+1] = Xt[(size_t)(n*8+b)*2+1];
        XTh[ro+2] = (_Float16)ax0; XTh[ro+3] = (_Float16)ax1;
        XTh[ro+4] = (_Float16)ay0; XTh[ro+5] = (_Float16)ay1;
    }
}

__global__ __launch_bounds__(64) void k_prop2_l0zrh(
    const _Float16* __restrict__ T1o, const _Float16* __restrict__ T1i,
    _Float16* __restrict__ T2o, _Float16* __restrict__ T2i, _Float16* __restrict__ XTh,
    const int* __restrict__ rp, const int* __restrict__ cs,
    const float* __restrict__ cwo, const float* __restrict__ cwi){
    int bx = blockIdx.x;
    int n = bx >> 1, sel = bx & 1;
    const _Float16* S = sel ? T1i : T1o;
    _Float16* U = sel ? T2i : T2o;
    const float* cw = sel ? cwi : cwo;
    int beg = rp[n], deg = rp[n+1]-beg;
    int nst = deg < MAXDEG ? deg : MAXDEG;
    __shared__ int s_o[MAXDEG]; __shared__ float s_w[MAXDEG];
    for (int j=threadIdx.x; j<nst; j+=64){
        s_o[j] = cs[beg+j]*512;
        s_w[j] = cw[beg+j];
    }
    __syncthreads();
    int off = threadIdx.x*8;
    {
        float a[8] = {0,0,0,0,0,0,0,0};
        for (int j=0;j<nst;j++){
            half8 v = *(const half8*)(S + s_o[j] + off);
            float w=s_w[j];
            #pragma unroll
            for (int e=0;e<8;e++) a[e]=fmaf(w,(float)v[e],a[e]);
        }
        for (int j=nst;j<deg;j++){
            half8 v = *(const half8*)(S + (size_t)cs[beg+j]*512 + off);
            float w=cw[beg+j];
            #pragma unroll
            for (int e=0;e<8;e++) a[e]=fmaf(w,(float)v[e],a[e]);
        }
        half8 p;
        #pragma unroll
        for (int e=0;e<8;e++) p[e]=(_Float16)a[e];
        *(half8*)(U + (size_t)n*512 + off) = p;
    }
    if (threadIdx.x < 8){
        int b = threadIdx.x;
        int xo = 2 + 2*sel;
        float a0=0,a1=0;
        for (int j=0;j<nst;j++){
            int src = s_o[j] >> 9;
            half2v v = *(const half2v*)(XTh + (size_t)src*256 + b*32 + xo);
            a0=fmaf(s_w[j],(float)v[0],a0); a1=fmaf(s_w[j],(float)v[1],a1);
        }
        for (int j=nst;j<deg;j++){
            int src = cs[beg+j];
            half2v v = *(const half2v*)(XTh + (size_t)src*256 + b*32 + xo);
            a0=fmaf(cw[beg+j],(float)v[0],a0); a1=fmaf(cw[beg+j],(float)v[1],a1);
        }
        size_t ro = (size_t)(n*8 + b)*32 + 6 + 2*sel;
        XTh[ro+0] = (_Float16)a0; XTh[ro+1] = (_Float16)a1;
    }
}

__global__ __launch_bounds__(128) void k_dual2x64h(
    const _Float16* __restrict__ h0h, const _Float16* __restrict__ h1h,
    _Float16* __restrict__ T1o, _Float16* __restrict__ T1i,
    const int* __restrict__ rp, const int* __restrict__ cs,
    const float* __restrict__ cwo, const float* __restrict__ cwi){
    int n = blockIdx.x;
    int beg = rp[n], deg = rp[n+1]-beg;
    int nst = deg < MAXDEG ? deg : MAXDEG;
    __shared__ int s_o[MAXDEG]; __shared__ float swo[MAXDEG], swi[MAXDEG];
    for (int j=threadIdx.x; j<nst; j+=128){
        s_o[j] = cs[beg+j]*512;
        swo[j] = cwo[beg+j]; swi[j] = cwi[beg+j];
    }
    __syncthreads();
    int off = threadIdx.x*8;            // within 1024-half output slab
    int b = off >> 7, c = off & 127;
    const _Float16* S = (c < 64) ? h0h : h1h;
    int soff = b*64 + (c & 63);
    float ao[8] = {0,0,0,0,0,0,0,0}, ai[8] = {0,0,0,0,0,0,0,0};
    for (int j=0;j<nst;j++){
        half8 v = *(const half8*)(S + s_o[j] + soff);
        float wo=swo[j], wi=swi[j];
        #pragma unroll
        for (int e=0;e<8;e++){
            float xv = (float)v[e];
            ao[e]=fmaf(wo,xv,ao[e]); ai[e]=fmaf(wi,xv,ai[e]);
        }
    }
    for (int j=nst;j<deg;j++){
        half8 v = *(const half8*)(S + (size_t)cs[beg+j]*512 + soff);
        float wo=cwo[beg+j], wi=cwi[beg+j];
        #pragma unroll
        for (int e=0;e<8;e++){
            float xv = (float)v[e];
            ao[e]=fmaf(wo,xv,ao[e]); ai[e]=fmaf(wi,xv,ai[e]);
        }
    }
    half8 po, pi;
    #pragma unroll
    for (int e=0;e<8;e++){ po[e]=(_Float16)ao[e]; pi[e]=(_Float16)ai[e]; }
    *(half8*)(T1o + (size_t)n*1024 + off) = po;
    *(half8*)(T1i + (size_t)n*1024 + off) = pi;
}

// ---------------- MFMA f16 GEMM: LDS-staged B (double-buffered), 32x32 wave tiles ----------------

struct KD { const _Float16* a; int st; };
struct GA { KD kd[20]; };

// wave wv: rows m0=bx*64+(wv&1)*32, cols (wv>>1)*32
// EPI 0 (NG=2): z=sig(g0), r=sig(g1); Z=z; Gout=(f16)(Hf*r)
// EPI 1 (NG=1): ht=tanh(g0); hn=z*Hf+(1-z)*ht; Hf=hn; Hh=(f16)hn
// EPI 2 (NG=1): EPI1 + fused proj via LDS cross-wave reduce
template<int NK, int NG, int EPI>
__global__ __launch_bounds__(256) void k_gemm(GA ga,
    const _Float16* __restrict__ wh0, const float* __restrict__ b0,
    const _Float16* __restrict__ wh1, const float* __restrict__ b1,
    float* __restrict__ Z, _Float16* __restrict__ Gout,
    float* __restrict__ Hf, _Float16* __restrict__ Hh,
    const float* __restrict__ Wo, const float* __restrict__ bo,
    float* __restrict__ out, int t){
    __shared__ _Float16 ldsb[2][NG*2048];
    __shared__ float spr[4][32];
    const int tid = threadIdx.x;
    const int lane = tid & 63, wv = tid >> 6, rl = lane & 15, kg = lane >> 4;
    const int m0 = blockIdx.x*64 + (wv&1)*32;
    const int cfb = (wv>>1)*2;
    const _Float16* wsrc[2] = {wh0, wh1};

    half8 srg[NG];
    half8 a0, a1, a0n, a1n;

    auto sload = [&](int ks){
        #pragma unroll
        for (int j=0;j<NG;j++)
            srg[j] = *(const half8*)(wsrc[j] + (size_t)ks*2048 + tid*8);
    };
    auto swrite = [&](int buf){
        #pragma unroll
        for (int j=0;j<NG;j++)
            *(half8*)&ldsb[buf][j*2048 + tid*8] = srg[j];
    };
    auto aload = [&](int ks, half8& x0, half8& x1){
        const _Float16* base = ga.kd[ks].a;
        const int st = ga.kd[ks].st;
        x0 = *(const half8*)(base + (size_t)(m0+rl)*st + kg*8);
        x1 = *(const half8*)(base + (size_t)(m0+16+rl)*st + kg*8);
    };

    f32x4 acc[NG][2][2];
    #pragma unroll
    for (int g=0; g<NG; ++g)
        #pragma unroll
        for (int cc=0; cc<2; ++cc)
            #pragma unroll
            for (int mr=0; mr<2; ++mr){
                acc[g][cc][mr][0]=0.f; acc[g][cc][mr][1]=0.f;
                acc[g][cc][mr][2]=0.f; acc[g][cc][mr][3]=0.f;
            }

    sload(0); swrite(0);
    if (NK>1) sload(1);
    aload(0, a0, a1);
    __syncthreads();
    for (int ks=0; ks<NK; ++ks){
        const int cur = ks & 1;
        if (ks+1 < NK){ swrite(cur^1); aload(ks+1, a0n, a1n); }
        if (ks+2 < NK) sload(ks+2);
        #pragma unroll
        for (int g=0; g<NG; ++g){
            #pragma unroll
            for (int cc=0; cc<2; ++cc){
                half8 bv = *(const half8*)&ldsb[cur][g*2048 + (cfb+cc)*512 + lane*8];
                acc[g][cc][0] = __builtin_amdgcn_mfma_f32_16x16x32_f16(a0, bv, acc[g][cc][0], 0, 0, 0);
                acc[g][cc][1] = __builtin_amdgcn_mfma_f32_16x16x32_f16(a1, bv, acc[g][cc][1], 0, 0, 0);
            }
        }
        __syncthreads();
        a0 = a0n; a1 = a1n;
    }

    if constexpr (EPI == 0){
        #pragma unroll
        for (int cc=0; cc<2; ++cc){
            const int col = (cfb+cc)*16 + rl;
            float bzv = b0[col], brv = b1[col];
            #pragma unroll
            for (int mr=0; mr<2; ++mr)
                #pragma unroll
                for (int i=0;i<4;i++){
                    int row = m0 + mr*16 + kg*4 + i;
                    float z = 1.f/(1.f+__expf(-(acc[0][cc][mr][i] + bzv)));
                    float r = 1.f/(1.f+__expf(-(acc[NG-1][cc][mr][i] + brv)));
                    size_t ix = (size_t)row*64 + col;
                    Z[ix] = z;
                    Gout[ix] = (_Float16)(Hf[ix]*r);
                }
        }
    } else {
        float pr[2][4] = {{0.f,0.f,0.f,0.f},{0.f,0.f,0.f,0.f}};
        #pragma unroll
        for (int cc=0; cc<2; ++cc){
            const int col = (cfb+cc)*16 + rl;
            float bv = b0[col];
            float wo_c = 0.f;
            if constexpr (EPI == 2) wo_c = Wo[col];
            #pragma unroll
            for (int mr=0; mr<2; ++mr)
                #pragma unroll
                for (int i=0;i<4;i++){
                    int row = m0 + mr*16 + kg*4 + i;
                    float ht = tanhf(acc[0][cc][mr][i] + bv);
                    size_t ix = (size_t)row*64 + col;
                    float z = Z[ix];
                    float hn = z*Hf[ix] + (1.f-z)*ht;
                    Hf[ix] = hn;
                    Hh[ix] = (_Float16)hn;
                    if constexpr (EPI == 2) pr[mr][i] = fmaf(hn, wo_c, pr[mr][i]);
                }
        }
        if constexpr (EPI == 2){
            #pragma unroll
            for (int mr=0; mr<2; ++mr)
                #pragma unroll
                for (int i=0;i<4;i++){
                    float v = pr[mr][i];
                    v += __shfl_xor(v, 1);
                    v += __shfl_xor(v, 2);
                    v += __shfl_xor(v, 4);
                    v += __shfl_xor(v, 8);
                    if (rl == 0) spr[wv][mr*16 + kg*4 + i] = v;
                }
            __syncthreads();
            if (tid < 64){
                int r = tid;
                float v = spr[r>>5][r&31] + spr[(r>>5)|2][r&31] + bo[0];
                int row = blockIdx.x*64 + r;
                int n = row >> 3, b = row & 7;
                out[(size_t)(b*SEQT + t)*NNODES + n] = v;
            }
        }
    }
}

// ---------------- launcher ----------------

extern "C" void kernel_launch(void* const* d_in, const int* in_sizes, int n_in,
                              void* d_out, int out_size, void* d_ws, size_t ws_size,
                              hipStream_t stream){
    (void)in_sizes; (void)n_in; (void)out_size; (void)ws_size;
    const float* x  = (const float*)d_in[0];
    const int*   ei = (const int*)d_in[1];
    const float* Wz[2] = {(const float*)d_in[2],  (const float*)d_in[8]};
    const float* bz[2] = {(const float*)d_in[3],  (const float*)d_in[9]};
    const float* Wr[2] = {(const float*)d_in[4],  (const float*)d_in[10]};
    const float* br[2] = {(const float*)d_in[5],  (const float*)d_in[11]};
    const float* Wh[2] = {(const float*)d_in[6],  (const float*)d_in[12]};
    const float* bh[2] = {(const float*)d_in[7],  (const float*)d_in[13]};
    const float* Wo = (const float*)d_in[14];
    const float* bo = (const float*)d_in[15];
    float* out = (float*)d_out;

    char* p = (char*)d_ws;
    auto alloc = [&](size_t bytes)->char*{
        char* r = p; p += (bytes + 255) & ~(size_t)255; return r;
    };
    const size_t H64  = (size_t)NB*64*2;
    const size_t H128 = (size_t)NB*128*2;
    const size_t F64  = (size_t)NB*64*4;

    _Float16* Xtph = (_Float16*)alloc((size_t)SEQT*NB*2*2);
    float*    h0f = (float*)alloc(F64);
    float*    h1f = (float*)alloc(F64);
    float*    Z0  = (float*)alloc(F64);
    float*    Z1  = (float*)alloc(F64);
    _Float16* h0h = (_Float16*)alloc(H64);
    _Float16* h1h = (_Float16*)alloc(H64);
    _Float16* XTh = (_Float16*)alloc((size_t)NB*32*2);
    _Float16* Th1o = (_Float16*)alloc(H64);
    _Float16* Th1i = (_Float16*)alloc(H64);
    _Float16* Th2o = (_Float16*)alloc(H64);
    _Float16* Th2i = (_Float16*)alloc(H64);
    _Float16* G0L0 = (_Float16*)alloc(H64);
    _Float16* G1o0 = (_Float16*)alloc(H64);
    _Float16* G1i0 = (_Float16*)alloc(H64);
    _Float16* G2o0 = (_Float16*)alloc(H64);
    _Float16* G2i0 = (_Float16*)alloc(H64);
    _Float16* T1o128 = (_Float16*)alloc(H128);
    _Float16* T1i128 = (_Float16*)alloc(H128);
    _Float16* U2o128 = (_Float16*)alloc(H128);
    _Float16* U2i128 = (_Float16*)alloc(H128);
    _Float16* G0p  = (_Float16*)alloc(H64);
    _Float16* G1o1 = (_Float16*)alloc(H64);
    _Float16* G1i1 = (_Float16*)alloc(H64);
    _Float16* G2o1 = (_Float16*)alloc(H64);
    _Float16* G2i1 = (_Float16*)alloc(H64);
    _Float16 *whl0[3], *whl1[3];
    for (int g=0; g<3; ++g){
        whl0[g] = (_Float16*)alloc((size_t)4*11*64*8*2);
        whl1[g] = (_Float16*)alloc((size_t)4*20*64*8*2);
    }
    int* deg_out = (int*)alloc(NNODES*4);
    int* deg_in  = (int*)alloc(NNODES*4);
    int* row_ptr = (int*)alloc((NNODES+1)*4);
    int* cursor  = (int*)alloc(NNODES*4);
    int* csr_src = (int*)alloc(NEDGES*4);
    float* csr_wo = (float*)alloc(NEDGES*4);
    float* csr_wi = (float*)alloc(NEDGES*4);

    hipMemsetAsync(deg_out, 0, NNODES*4, stream);
    hipMemsetAsync(deg_in,  0, NNODES*4, stream);
    hipMemsetAsync(cursor,  0, NNODES*4, stream);
    hipMemsetAsync(h0f, 0, F64, stream);
    hipMemsetAsync(h1f, 0, F64, stream);
    hipMemsetAsync(h0h, 0, H64, stream);
    hipMemsetAsync(h1h, 0, H64, stream);
    hipMemsetAsync(XTh, 0, (size_t)NB*32*2, stream);

    count_deg_k<<<(NEDGES+255)/256, 256, 0, stream>>>(ei, deg_out, deg_in);
    scan_k<<<1, 256, 0, stream>>>(deg_in, row_ptr);
    fill_csr_k<<<(NEDGES+255)/256, 256, 0, stream>>>(ei, deg_out, deg_in, row_ptr,
                                                     cursor, csr_src, csr_wo, csr_wi);
    prepack_x_k<<<(SEQT*NB*2+255)/256, 256, 0, stream>>>(x, Xtph);
    const float* Wptr0[3] = {Wz[0], Wr[0], Wh[0]};
    const float* Wptr1[3] = {Wz[1], Wr[1], Wh[1]};
    for (int g=0; g<3; ++g){
        pack_l0_k<<<(4*11*64+255)/256, 256, 0, stream>>>(Wptr0[g], whl0[g]);
        pack_l1_k<<<(4*20*64+255)/256, 256, 0, stream>>>(Wptr1[g], whl1[g]);
    }

    // GEMM K-block descriptor tables (strides in halves)
    GA gaL0zr = {}, gaL0h = {}, gaL1zr = {}, gaL1h = {};
    {
        const _Float16* t64[5] = {h0h, Th1o, Th1i, Th2o, Th2i};
        gaL0zr.kd[0] = {XTh, 32};
        for (int s=0; s<5; ++s){
            gaL0zr.kd[1+2*s] = {t64[s], 64};
            gaL0zr.kd[2+2*s] = {t64[s]+32, 64};
        }
        const _Float16* g64[5] = {G0L0, G1o0, G1i0, G2o0, G2i0};
        gaL0h.kd[0] = {XTh, 32};
        for (int s=0; s<5; ++s){
            gaL0h.kd[1+2*s] = {g64[s], 64};
            gaL0h.kd[2+2*s] = {g64[s]+32, 64};
        }
        gaL1zr.kd[0] = {h0h, 64};    gaL1zr.kd[1] = {h0h+32, 64};
        gaL1zr.kd[2] = {h1h, 64};    gaL1zr.kd[3] = {h1h+32, 64};
        const _Float16* t128[4] = {T1o128, T1i128, U2o128, U2i128};
        for (int s=0; s<4; ++s)
            for (int q=0; q<4; ++q)
                gaL1zr.kd[4+4*s+q] = {t128[s]+32*q, 128};
        gaL1h.kd[0] = {h0h, 64};  gaL1h.kd[1] = {h0h+32, 64};
        gaL1h.kd[2] = {G0p, 64};  gaL1h.kd[3] = {G0p+32, 64};
        const _Float16* gh[4] = {G1o1, G1i1, G2o1, G2i1};
        for (int s=0; s<4; ++s){
            gaL1h.kd[4+4*s+0] = {t128[s], 128};
            gaL1h.kd[4+4*s+1] = {t128[s]+32, 128};
            gaL1h.kd[4+4*s+2] = {gh[s], 64};
            gaL1h.kd[4+4*s+3] = {gh[s]+32, 64};
        }
    }

    for (int t=0; t<SEQT; ++t){
        // ---- layer 0 ----
        k_dual_l0zrh<<<NNODES, 64, 0, stream>>>(h0h, Xtph + (size_t)t*NB*2, Th1o, Th1i, XTh,
                                                row_ptr, csr_src, csr_wo, csr_wi);
        k_prop2_l0zrh<<<2*NNODES, 64, 0, stream>>>(Th1o, Th1i, Th2o, Th2i, XTh,
                                                row_ptr, csr_src, csr_wo, csr_wi);
        k_gemm<11,2,0><<<NB/64, 256, 0, stream>>>(gaL0zr,
            whl0[0], bz[0], whl0[1], br[0],
            Z0, G0L0, h0f, nullptr, nullptr, nullptr, nullptr, 0);
        k_dualh<64><<<NNODES, 64, 0, stream>>>(G0L0, G1o0, G1i0, row_ptr, csr_src, csr_wo, csr_wi);
        k_prop2h<64><<<2*NNODES, 64, 0, stream>>>(G1o0, G1i0, G2o0, G2i0,
                                                row_ptr, csr_src, csr_wo, csr_wi);
        k_gemm<11,1,1><<<NB/64, 256, 0, stream>>>(gaL0h,
            whl0[2], bh[0], nullptr, nullptr,
            Z0, nullptr, h0f, h0h, nullptr, nullptr, nullptr, 0);
        // ---- layer 1 ----
        k_dual2x64h<<<NNODES, 128, 0, stream>>>(h0h, h1h, T1o128, T1i128,
                                                row_ptr, csr_src, csr_wo, csr_wi);
        k_prop2h<128><<<2*NNODES, 128, 0, stream>>>(T1o128, T1i128, U2o128, U2i128,
                                                row_ptr, csr_src, csr_wo, csr_wi);
        k_gemm<20,2,0><<<NB/64, 256, 0, stream>>>(gaL1zr,
            whl1[0], bz[1], whl1[1], br[1],
            Z1, G0p, h1f, nullptr, nullptr, nullptr, nullptr, 0);
        k_dualh<64><<<NNODES, 64, 0, stream>>>(G0p, G1o1, G1i1, row_ptr, csr_src, csr_wo, csr_wi);
        k_prop2h<64><<<2*NNODES, 64, 0, stream>>>(G1o1, G1i1, G2o1, G2i1,
                                                row_ptr, csr_src, csr_wo, csr_wi);
        k_gemm<20,1,2><<<NB/64, 256, 0, stream>>>(gaL1h,
            whl1[2], bh[1], nullptr, nullptr,
            Z1, nullptr, h1f, h1h, Wo, bo, out, t);
    }
}